// Round 1
// baseline (3272.708 us; speedup 1.0000x reference)
//
#include <hip/hip_runtime.h>
#include <math.h>

// Problem constants (B,T,C fixed by setup_inputs)
#define Bb    2
#define Tt    2048
#define Cc    2048
#define Hh    16
#define DH    128      // head_dim
#define DSTD  120      // head_dim - R
#define FUSED 6144     // 3*C
#define Mm    4096     // B*T

// ---------------------------------------------------------------------------
// GEMM: C[M,N] = A[M,K] * B[N,K]^T   (both operands K-contiguous row-major)
// 128x128 tile, BK=16, 256 threads, 8x8 micro-tile.
// MODE 0: plain store to out[M,N]
// MODE 1: scatter epilogue -> routed Qf/Kf/V [B,H,T,128] with ws/wr scaling
// ---------------------------------------------------------------------------
template <int MODE>
__global__ __launch_bounds__(256)
void gemm_bt(const float* __restrict__ A, const float* __restrict__ Bw,
             float* __restrict__ out,
             float* __restrict__ Qf, float* __restrict__ Kf, float* __restrict__ Vv,
             const float* __restrict__ w_std, const float* __restrict__ w_rec,
             int N, int K)
{
    __shared__ float As[16][132];   // k-major, padded stride 132 (16B-aligned, bank-spread)
    __shared__ float Bs[16][132];
    __shared__ float lws[Hh];
    __shared__ float lwr[Hh];
    __shared__ int   lra[Hh];

    const int tid = threadIdx.x;
    const int tx = tid & 15, ty = tid >> 4;
    const int m0 = blockIdx.y * 128;
    const int n0 = blockIdx.x * 128;

    if (MODE == 1 && tid < Hh) {
        float a  = w_std[tid]; float ac = a < 1e-8f ? 1e-8f : a;
        lws[tid] = sqrtf(ac);
        float r  = w_rec[tid]; float rc = r < 1e-8f ? 1e-8f : r;
        lwr[tid] = sqrtf(rc);
        lra[tid] = (r > 0.1f) ? 1 : 0;   // THRESHOLD = 0.1
    }

    float acc[8][8];
#pragma unroll
    for (int i = 0; i < 8; ++i)
#pragma unroll
        for (int j = 0; j < 8; ++j) acc[i][j] = 0.f;

    const float* Aptr = A  + (size_t)m0 * K;
    const float* Bptr = Bw + (size_t)n0 * K;

    for (int kt = 0; kt < K; kt += 16) {
        // ---- stage 128x16 tiles of A and B (coalesced 64B segments) ----
#pragma unroll
        for (int s = 0; s < 2; ++s) {
            int chunk = tid + s * 256;
            int r  = chunk >> 2;            // 0..127 row within tile
            int c4 = (chunk & 3) << 2;      // k-offset 0,4,8,12
            float4 av = *(const float4*)(Aptr + (size_t)r * K + kt + c4);
            As[c4 + 0][r] = av.x; As[c4 + 1][r] = av.y;
            As[c4 + 2][r] = av.z; As[c4 + 3][r] = av.w;
            float4 bv = *(const float4*)(Bptr + (size_t)r * K + kt + c4);
            Bs[c4 + 0][r] = bv.x; Bs[c4 + 1][r] = bv.y;
            Bs[c4 + 2][r] = bv.z; Bs[c4 + 3][r] = bv.w;
        }
        __syncthreads();

        // ---- 8x8 micro-tile: rows 8ty..8ty+7, cols {4tx..+3} U {64+4tx..+3} ----
#pragma unroll
        for (int k = 0; k < 16; ++k) {
            float4 a0 = *(const float4*)&As[k][ty * 8];
            float4 a1 = *(const float4*)&As[k][ty * 8 + 4];
            float4 b0 = *(const float4*)&Bs[k][tx * 4];
            float4 b1 = *(const float4*)&Bs[k][64 + tx * 4];
            float ar[8] = {a0.x, a0.y, a0.z, a0.w, a1.x, a1.y, a1.z, a1.w};
            float br[8] = {b0.x, b0.y, b0.z, b0.w, b1.x, b1.y, b1.z, b1.w};
#pragma unroll
            for (int i = 0; i < 8; ++i)
#pragma unroll
                for (int j = 0; j < 8; ++j)
                    acc[i][j] += ar[i] * br[j];
        }
        __syncthreads();
    }

    if (MODE == 0) {
#pragma unroll
        for (int i = 0; i < 8; ++i) {
            int m = m0 + ty * 8 + i;
#pragma unroll
            for (int g = 0; g < 2; ++g) {
                float4 v = make_float4(acc[i][g * 4 + 0], acc[i][g * 4 + 1],
                                       acc[i][g * 4 + 2], acc[i][g * 4 + 3]);
                *(float4*)(out + (size_t)m * N + n0 + g * 64 + tx * 4) = v;
            }
        }
    } else {
        // scatter into routed Q/K/V buffers, layout [B,H,T,128]
#pragma unroll
        for (int i = 0; i < 8; ++i) {
            int m = m0 + ty * 8 + i;
            int bb = m >> 11, t = m & 2047;
#pragma unroll
            for (int g = 0; g < 2; ++g) {
#pragma unroll
                for (int c = 0; c < 4; ++c) {
                    int f = n0 + g * 64 + tx * 4 + c;
                    float v = acc[i][g * 4 + c];
                    float* dst; int h, d; float sc;
                    if (f < 1920)      { h = f / 120;  d = f - h * 120;  dst = Qf; sc = lws[h]; }
                    else if (f < 3840) { int gg = f - 1920; h = gg / 120; d = gg - h * 120; dst = Kf; sc = lws[h]; }
                    else if (f < 5888) { int gg = f - 3840; h = gg >> 7;  d = gg & 127;     dst = Vv; sc = 1.f; }
                    else if (f < 6016) { int gg = f - 5888; h = gg >> 3;  d = DSTD + (gg & 7);
                                         if (lra[h]) { dst = Kf; sc = lwr[h]; } else { dst = Qf; sc = lws[h]; } }
                    else               { int gg = f - 6016; h = gg >> 3;  d = DSTD + (gg & 7);
                                         if (lra[h]) { dst = Qf; sc = lwr[h]; } else { dst = Kf; sc = lws[h]; } }
                    dst[((((size_t)bb * Hh + h) * Tt + t) << 7) + d] = v * sc;
                }
            }
        }
    }
}

// ---------------------------------------------------------------------------
// Flash-style causal attention, fp32. One block = (b,h, 32 q-rows).
// QT=KT=32, 256 threads (16x16), 2x2 micro for QK^T, online softmax,
// PV with P stored k-major. ~57KB LDS.
// ---------------------------------------------------------------------------
__global__ __launch_bounds__(256)
void attn_fwd(const float* __restrict__ Qf, const float* __restrict__ Kf,
              const float* __restrict__ Vv, float* __restrict__ out)
{
    __shared__ float Qs[128][32];   // d-major
    __shared__ float Ks[128][32];   // d-major
    __shared__ float Vs[32][128];   // row-major
    __shared__ float Pt[32][36];    // P^T: [k][i], padded
    __shared__ float pm[16][32];    // partial row max [txgroup][row]
    __shared__ float psum[16][32];  // partial row sum
    __shared__ float rowm[32], rowl[32], rowsc[32];

    const int tid = threadIdx.x;
    const int tx = tid & 15, ty = tid >> 4;
    const int bh = blockIdx.y;          // b*16+h
    const int b = bh >> 4, h = bh & 15;
    const int qt = blockIdx.x;
    const int q0 = qt * 32;

    const float* Qb = Qf + ((size_t)bh * Tt << 7);
    const float* Kb = Kf + ((size_t)bh * Tt << 7);
    const float* Vb = Vv + ((size_t)bh * Tt << 7);

    if (tid < 32) { rowm[tid] = -INFINITY; rowl[tid] = 0.f; }

    // stage Q tile once, fold in softmax scale 1/sqrt(128)
    const float qsc = 0.08838834764831845f;
#pragma unroll
    for (int s = 0; s < 4; ++s) {
        int chunk = tid + s * 256;
        int c = (chunk & 7) | (((chunk >> 8) & 3) << 3);  // f4-chunk 0..31
        int r = (chunk >> 3) & 31;                        // row 0..31
        float4 v = *(const float4*)(Qb + (size_t)(q0 + r) * DH + c * 4);
        Qs[c * 4 + 0][r] = v.x * qsc; Qs[c * 4 + 1][r] = v.y * qsc;
        Qs[c * 4 + 2][r] = v.z * qsc; Qs[c * 4 + 3][r] = v.w * qsc;
    }

    float o0[8], o1[8];
#pragma unroll
    for (int j = 0; j < 8; ++j) { o0[j] = 0.f; o1[j] = 0.f; }

    for (int kti = 0; kti <= qt; ++kti) {
        const int k0 = kti * 32;
        // ---- stage K (transposed) and V (row-major) ----
#pragma unroll
        for (int s = 0; s < 4; ++s) {
            int chunk = tid + s * 256;
            int c = (chunk & 7) | (((chunk >> 8) & 3) << 3);
            int r = (chunk >> 3) & 31;
            float4 v = *(const float4*)(Kb + (size_t)(k0 + r) * DH + c * 4);
            Ks[c * 4 + 0][r] = v.x; Ks[c * 4 + 1][r] = v.y;
            Ks[c * 4 + 2][r] = v.z; Ks[c * 4 + 3][r] = v.w;
            int rv = chunk >> 5;
            int cv = chunk & 31;
            float4 vv = *(const float4*)(Vb + (size_t)(k0 + rv) * DH + cv * 4);
            *(float4*)&Vs[rv][cv * 4] = vv;
        }
        __syncthreads();

        // ---- S = Q K^T (2x2 per thread) ----
        float s00 = 0.f, s01 = 0.f, s10 = 0.f, s11 = 0.f;
#pragma unroll 16
        for (int d = 0; d < 128; ++d) {
            float2 q = *(const float2*)&Qs[d][ty * 2];
            float2 k = *(const float2*)&Ks[d][tx * 2];
            s00 += q.x * k.x; s01 += q.x * k.y;
            s10 += q.y * k.x; s11 += q.y * k.y;
        }
        if (kti == qt) {  // causal mask (diagonal tile only)
            int qg0 = q0 + ty * 2, qg1 = qg0 + 1;
            int kg0 = k0 + tx * 2, kg1 = kg0 + 1;
            if (kg0 > qg0) s00 = -INFINITY;
            if (kg1 > qg0) s01 = -INFINITY;
            if (kg0 > qg1) s10 = -INFINITY;
            if (kg1 > qg1) s11 = -INFINITY;
        }

        // ---- online softmax: row max ----
        pm[tx][ty * 2]     = fmaxf(s00, s01);
        pm[tx][ty * 2 + 1] = fmaxf(s10, s11);
        __syncthreads();
        if (tid < 32) {
            float mo = rowm[tid];
            float mx = mo;
#pragma unroll
            for (int p = 0; p < 16; ++p) mx = fmaxf(mx, pm[p][tid]);
            float sc = expf(mo - mx);   // mo = -inf on first tile -> 0
            rowm[tid]  = mx;
            rowsc[tid] = sc;
            rowl[tid] *= sc;
        }
        __syncthreads();

        // ---- P = exp(S - m), partial sums, store P^T ----
        float m0v = rowm[ty * 2], m1v = rowm[ty * 2 + 1];
        float p00 = expf(s00 - m0v), p01 = expf(s01 - m0v);
        float p10 = expf(s10 - m1v), p11 = expf(s11 - m1v);
        Pt[tx * 2    ][ty * 2    ] = p00;
        Pt[tx * 2 + 1][ty * 2    ] = p01;
        Pt[tx * 2    ][ty * 2 + 1] = p10;
        Pt[tx * 2 + 1][ty * 2 + 1] = p11;
        psum[tx][ty * 2]     = p00 + p01;
        psum[tx][ty * 2 + 1] = p10 + p11;
        __syncthreads();
        if (tid < 32) {
            float ssum = 0.f;
#pragma unroll
            for (int p = 0; p < 16; ++p) ssum += psum[p][tid];
            rowl[tid] += ssum;
        }

        // ---- rescale O, then O += P V ----
        float sc0 = rowsc[ty * 2], sc1 = rowsc[ty * 2 + 1];
#pragma unroll
        for (int j = 0; j < 8; ++j) { o0[j] *= sc0; o1[j] *= sc1; }
#pragma unroll 8
        for (int k = 0; k < 32; ++k) {
            float2 p  = *(const float2*)&Pt[k][ty * 2];
            float4 v0 = *(const float4*)&Vs[k][tx * 4];
            float4 v1 = *(const float4*)&Vs[k][64 + tx * 4];
            o0[0] += p.x * v0.x; o0[1] += p.x * v0.y; o0[2] += p.x * v0.z; o0[3] += p.x * v0.w;
            o0[4] += p.x * v1.x; o0[5] += p.x * v1.y; o0[6] += p.x * v1.z; o0[7] += p.x * v1.w;
            o1[0] += p.y * v0.x; o1[1] += p.y * v0.y; o1[2] += p.y * v0.z; o1[3] += p.y * v0.w;
            o1[4] += p.y * v1.x; o1[5] += p.y * v1.y; o1[6] += p.y * v1.z; o1[7] += p.y * v1.w;
        }
        __syncthreads();
    }

    // ---- finalize: O / l, write att[b, t, h*128 + d] ----
    float inv0 = 1.f / rowl[ty * 2];
    float inv1 = 1.f / rowl[ty * 2 + 1];
    float* ob0 = out + ((size_t)(b * Tt + q0 + ty * 2) * Cc) + h * DH;
    float* ob1 = ob0 + Cc;
    *(float4*)(ob0 + tx * 4)      = make_float4(o0[0] * inv0, o0[1] * inv0, o0[2] * inv0, o0[3] * inv0);
    *(float4*)(ob0 + 64 + tx * 4) = make_float4(o0[4] * inv0, o0[5] * inv0, o0[6] * inv0, o0[7] * inv0);
    *(float4*)(ob1 + tx * 4)      = make_float4(o1[0] * inv1, o1[1] * inv1, o1[2] * inv1, o1[3] * inv1);
    *(float4*)(ob1 + 64 + tx * 4) = make_float4(o1[4] * inv1, o1[5] * inv1, o1[6] * inv1, o1[7] * inv1);
}

// ---------------------------------------------------------------------------
extern "C" void kernel_launch(void* const* d_in, const int* in_sizes, int n_in,
                              void* d_out, int out_size, void* d_ws, size_t ws_size,
                              hipStream_t stream) {
    const float* x      = (const float*)d_in[0];  // [B,T,C]
    const float* W_attn = (const float*)d_in[1];  // [6144, 2048]
    const float* W_proj = (const float*)d_in[2];  // [2048, 2048]
    const float* w_std  = (const float*)d_in[3];  // [16]
    const float* w_rec  = (const float*)d_in[4];  // [16]
    float* outp = (float*)d_out;

    // Workspace layout (needs 4 * 8388608 * 4B = 128 MiB)
    float* wsf = (float*)d_ws;
    const size_t SEG = (size_t)Bb * Hh * Tt * DH;  // 8,388,608 floats
    float* Qf  = wsf;
    float* Kf  = wsf + SEG;
    float* Vv  = wsf + 2 * SEG;
    float* att = wsf + 3 * SEG;

    // 1) fused = x @ W_attn^T, scatter into routed Qf/Kf/V
    gemm_bt<1><<<dim3(FUSED / 128, Mm / 128), dim3(256), 0, stream>>>(
        x, W_attn, nullptr, Qf, Kf, Vv, w_std, w_rec, FUSED, Cc);

    // 2) causal attention
    attn_fwd<<<dim3(Tt / 32, Bb * Hh), dim3(256), 0, stream>>>(Qf, Kf, Vv, att);

    // 3) out = att @ W_proj^T
    gemm_bt<0><<<dim3(Cc / 128, Mm / 128), dim3(256), 0, stream>>>(
        att, W_proj, outp, nullptr, nullptr, nullptr, nullptr, nullptr, Cc, Cc);
}

// Round 2
// 498.107 us; speedup vs baseline: 6.5703x; 6.5703x over previous
//
#include <hip/hip_runtime.h>
#include <math.h>

#define Bb 2
#define Tt 2048
#define Cc 2048
#define Hh 16
#define DH 128
#define FUSED 6144
#define Mm 4096
#define QSC 0.08838834764831845f   // 1/sqrt(128)

typedef __bf16 bf16x8 __attribute__((ext_vector_type(8)));
typedef float  f32x4  __attribute__((ext_vector_type(4)));

__device__ __forceinline__ unsigned short f2bf(float f) {
  unsigned int u = __float_as_uint(f);
  u = (u + 0x7fffu + ((u >> 16) & 1u)) >> 16;   // RNE
  return (unsigned short)u;
}

__device__ __forceinline__ void gload16(const void* src, void* lds) {
  __builtin_amdgcn_global_load_lds((const __attribute__((address_space(1))) void*)src,
                                   (__attribute__((address_space(3))) void*)lds, 16, 0, 0);
}

// ---------------------------------------------------------------------------
// fp32 -> bf16 convert (grid-stride, float4)
// ---------------------------------------------------------------------------
__global__ void f2bf_arr(const float* __restrict__ src, unsigned short* __restrict__ dst, int n)
{
  int i = (blockIdx.x * blockDim.x + threadIdx.x) * 4;
  int stride = gridDim.x * blockDim.x * 4;
  for (; i < n; i += stride) {
    float4 v = *(const float4*)&src[i];
    ushort4 o;
    o.x = f2bf(v.x); o.y = f2bf(v.y); o.z = f2bf(v.z); o.w = f2bf(v.w);
    *(ushort4*)&dst[i] = o;
  }
}

// ---------------------------------------------------------------------------
// bf16 MFMA GEMM: C[M,N] = A[M,K] * B[N,K]^T, both bf16 row-major k-contiguous.
// 128x128 tile, BK=64, 4 waves (2x2, each 64x64 out), global_load_lds w=16,
// LDS linear dest + pre-swizzled global source; reads use chunk ^= (row&7)
// -> conflict-free ds_read_b128 (8 bank-quads x 8 lanes = floor).
// MODE 0: fp32 store to out[M,N].  MODE 1: routed bf16 scatter to Q/K/V.
// ---------------------------------------------------------------------------
template <int MODE>
__global__ __launch_bounds__(256)
void gemm_bf16(const unsigned short* __restrict__ A, const unsigned short* __restrict__ Bw,
               float* __restrict__ out,
               unsigned short* __restrict__ Qb, unsigned short* __restrict__ Kb,
               unsigned short* __restrict__ Vb,
               const float* __restrict__ w_std, const float* __restrict__ w_rec,
               int N, int K)
{
  __shared__ unsigned short As[128 * 64];
  __shared__ unsigned short Bs[128 * 64];
  __shared__ float lws[Hh], lwr[Hh];
  __shared__ int   lra[Hh];

  const int tid  = threadIdx.x;
  const int lane = tid & 63;
  const int w    = tid >> 6;
  const int wr   = w >> 1, wc = w & 1;
  const int lrow = lane & 15, lgrp = lane >> 4;
  const int m0 = blockIdx.y * 128;
  const int n0 = blockIdx.x * 128;

  if (MODE == 1 && tid < Hh) {
    float a = w_std[tid]; lws[tid] = sqrtf(a < 1e-8f ? 1e-8f : a);
    float r = w_rec[tid]; lwr[tid] = sqrtf(r < 1e-8f ? 1e-8f : r);
    lra[tid] = (r > 0.1f) ? 1 : 0;
  }

  f32x4 acc[4][4] = {};

  for (int kt = 0; kt < K; kt += 64) {
#pragma unroll
    for (int c = 0; c < 4; ++c) {
      int base16 = (c * 4 + w) * 64;          // wave-uniform 16B-chunk base
      int o16 = base16 + lane;
      int rr = o16 >> 3, cc = o16 & 7;        // row 0..127, chunk 0..7
      int csw = (cc ^ (rr & 7)) << 3;
      gload16(A  + (size_t)(m0 + rr) * K + kt + csw, As + base16 * 8);
      gload16(Bw + (size_t)(n0 + rr) * K + kt + csw, Bs + base16 * 8);
    }
    __syncthreads();

#pragma unroll
    for (int s = 0; s < 2; ++s) {
      bf16x8 af[4], bfr[4];
#pragma unroll
      for (int i = 0; i < 4; ++i) {
        int row = wr * 64 + i * 16 + lrow;
        int ch  = s * 4 + lgrp;
        af[i]  = *(const bf16x8*)&As[row * 64 + ((ch ^ (row & 7)) << 3)];
        int col = wc * 64 + i * 16 + lrow;
        bfr[i] = *(const bf16x8*)&Bs[col * 64 + ((ch ^ (col & 7)) << 3)];
      }
#pragma unroll
      for (int i = 0; i < 4; ++i)
#pragma unroll
        for (int j = 0; j < 4; ++j)
          acc[i][j] = __builtin_amdgcn_mfma_f32_16x16x32_bf16(af[i], bfr[j], acc[i][j], 0, 0, 0);
    }
    __syncthreads();
  }

  if (MODE == 0) {
#pragma unroll
    for (int i = 0; i < 4; ++i)
#pragma unroll
      for (int r = 0; r < 4; ++r) {
        int m = m0 + wr * 64 + i * 16 + lgrp * 4 + r;
#pragma unroll
        for (int j = 0; j < 4; ++j) {
          int n = n0 + wc * 64 + j * 16 + lrow;
          out[(size_t)m * N + n] = acc[i][j][r];
        }
      }
  } else {
#pragma unroll
    for (int i = 0; i < 4; ++i)
#pragma unroll
      for (int r = 0; r < 4; ++r) {
        int m = m0 + wr * 64 + i * 16 + lgrp * 4 + r;
        int b = m >> 11, t = m & 2047;
#pragma unroll
        for (int j = 0; j < 4; ++j) {
          int f = n0 + wc * 64 + j * 16 + lrow;
          float v = acc[i][j][r];
          unsigned short* dst; int h, d; float sc;
          if (f < 1920)      { h = f / 120; d = f - h * 120; dst = Qb; sc = lws[h] * QSC; }
          else if (f < 3840) { int g = f - 1920; h = g / 120; d = g - h * 120; dst = Kb; sc = lws[h]; }
          else if (f < 5888) { int g = f - 3840; h = g >> 7; d = g & 127; dst = Vb; sc = 1.f; }
          else if (f < 6016) { int g = f - 5888; h = g >> 3; d = 120 + (g & 7);
                               if (lra[h]) { dst = Kb; sc = lwr[h]; }
                               else        { dst = Qb; sc = lws[h] * QSC; } }
          else               { int g = f - 6016; h = g >> 3; d = 120 + (g & 7);
                               if (lra[h]) { dst = Qb; sc = lwr[h] * QSC; }
                               else        { dst = Kb; sc = lws[h]; } }
          dst[((((size_t)b * Hh + h) * Tt + t) << 7) + d] = f2bf(v * sc);
        }
      }
  }
}

// ---------------------------------------------------------------------------
// V[bh][t][d] -> Vt[bh][d][t] (bf16), 64x128 tiles via LDS
// ---------------------------------------------------------------------------
__global__ __launch_bounds__(256)
void vtrans(const unsigned short* __restrict__ Vb, unsigned short* __restrict__ Vtb)
{
  __shared__ unsigned short Vs[64 * 128];
  const int tid = threadIdx.x;
  const int bh = blockIdx.y, t0 = blockIdx.x * 64;
  const unsigned short* src = Vb + ((size_t)bh * Tt + t0) * DH;
#pragma unroll
  for (int c = 0; c < 4; ++c) {
    int u = c * 256 + tid;            // 16B unit
    int row = u >> 4, ch = u & 15;
    *(uint4*)&Vs[row * 128 + ch * 8] = *(const uint4*)&src[(size_t)row * DH + ch * 8];
  }
  __syncthreads();
  unsigned short* dstb = Vtb + (size_t)bh * DH * Tt + t0;
#pragma unroll
  for (int c = 0; c < 4; ++c) {
    int u = c * 256 + tid;
    int d = u & 127, tc = u >> 7;     // d 0..127, t-chunk 0..7
    unsigned short tmp[8];
#pragma unroll
    for (int j = 0; j < 8; ++j) tmp[j] = Vs[(tc * 8 + j) * 128 + d];
    *(uint4*)&dstb[(size_t)d * Tt + tc * 8] = *(uint4*)tmp;
  }
}

// ---------------------------------------------------------------------------
// MFMA flash attention. Block = (bh, 64 q-rows), 4 waves x 16 q-rows each.
// Q pre-scaled by ws*1/sqrt(128). K[64][128] & Vt[128][64] staged per kv-tile
// via global_load_lds (pre-swizzled source). Softmax fully wave-parallel in
// registers (shfl_xor across 16-lane column groups). P -> bf16 -> per-wave LDS.
// ---------------------------------------------------------------------------
__global__ __launch_bounds__(256)
void attn_mfma(const unsigned short* __restrict__ Qb, const unsigned short* __restrict__ Kb,
               const unsigned short* __restrict__ Vtb, unsigned short* __restrict__ attb)
{
  __shared__ unsigned short Kt[64 * 128];
  __shared__ unsigned short Vt[128 * 64];
  __shared__ unsigned short QP[64 * 128];   // Q staging, then per-wave P tiles

  const int tid = threadIdx.x, lane = tid & 63, w = tid >> 6;
  const int lrow = lane & 15, lgrp = lane >> 4;
  const int bh = blockIdx.y;
  const int qt = 31 - blockIdx.x;           // heavy diagonal blocks first
  const int q0 = qt * 64;
  const unsigned short* Qh = Qb  + (size_t)bh * Tt * DH;
  const unsigned short* Kh = Kb  + (size_t)bh * Tt * DH;
  const unsigned short* Vh = Vtb + (size_t)bh * DH * Tt;

  // stage Q tile [64][128]
#pragma unroll
  for (int c = 0; c < 4; ++c) {
    int base16 = (c * 4 + w) * 64;
    int o16 = base16 + lane;
    int rr = o16 >> 4, cc = o16 & 15;
    gload16(Qh + (size_t)(q0 + rr) * DH + ((cc ^ (rr & 7)) << 3), QP + base16 * 8);
  }
  __syncthreads();

  bf16x8 qf[4];
#pragma unroll
  for (int s = 0; s < 4; ++s) {
    int row = w * 16 + lrow;
    int ch  = s * 4 + lgrp;
    qf[s] = *(const bf16x8*)&QP[row * 128 + ((ch ^ (row & 7)) << 3)];
  }
  __syncthreads();  // Q frags hoisted; QP region now reused for P

  f32x4 o[8] = {};
  float mrun[4], lrun[4];
#pragma unroll
  for (int r = 0; r < 4; ++r) { mrun[r] = -INFINITY; lrun[r] = 0.f; }
  unsigned short* Pw = QP + w * 1024;   // per-wave P [16][64]

  for (int t = 0; t <= qt; ++t) {
    const int kv0 = t * 64;
#pragma unroll
    for (int c = 0; c < 4; ++c) {
      int base16 = (c * 4 + w) * 64;
      int o16 = base16 + lane;
      { int rr = o16 >> 4, cc = o16 & 15;
        gload16(Kh + (size_t)(kv0 + rr) * DH + ((cc ^ (rr & 7)) << 3), Kt + base16 * 8); }
      { int rr = o16 >> 3, cc = o16 & 7;
        gload16(Vh + (size_t)rr * Tt + kv0 + ((cc ^ (rr & 7)) << 3), Vt + base16 * 8); }
    }
    __syncthreads();

    // ---- S = Q K^T : 16 q-rows x 64 kv per wave ----
    f32x4 sv[4] = {};
#pragma unroll
    for (int ks = 0; ks < 4; ++ks)
#pragma unroll
      for (int j = 0; j < 4; ++j) {
        int krow = j * 16 + lrow;
        int ch   = ks * 4 + lgrp;
        bf16x8 kf = *(const bf16x8*)&Kt[krow * 128 + ((ch ^ (krow & 7)) << 3)];
        sv[j] = __builtin_amdgcn_mfma_f32_16x16x32_bf16(qf[ks], kf, sv[j], 0, 0, 0);
      }

    // ---- online softmax (all lanes parallel) ----
    float sc[4];
#pragma unroll
    for (int r = 0; r < 4; ++r) {
      if (t == qt) {
        int qrow = q0 + w * 16 + lgrp * 4 + r;
#pragma unroll
        for (int j = 0; j < 4; ++j) {
          int kv = kv0 + j * 16 + lrow;
          if (kv > qrow) sv[j][r] = -INFINITY;
        }
      }
      float m_ = fmaxf(fmaxf(sv[0][r], sv[1][r]), fmaxf(sv[2][r], sv[3][r]));
      m_ = fmaxf(m_, __shfl_xor(m_, 1));
      m_ = fmaxf(m_, __shfl_xor(m_, 2));
      m_ = fmaxf(m_, __shfl_xor(m_, 4));
      m_ = fmaxf(m_, __shfl_xor(m_, 8));
      float mn = fmaxf(mrun[r], m_);
      sc[r] = __expf(mrun[r] - mn);
      mrun[r] = mn;
      float rs = 0.f;
#pragma unroll
      for (int j = 0; j < 4; ++j) {
        float p = __expf(sv[j][r] - mn);
        sv[j][r] = p;
        rs += p;
      }
      rs += __shfl_xor(rs, 1);
      rs += __shfl_xor(rs, 2);
      rs += __shfl_xor(rs, 4);
      rs += __shfl_xor(rs, 8);
      lrun[r] = lrun[r] * sc[r] + rs;
    }

    // ---- rescale O ----
#pragma unroll
    for (int n = 0; n < 8; ++n)
#pragma unroll
      for (int r = 0; r < 4; ++r) o[n][r] *= sc[r];

    // ---- P -> bf16 -> per-wave LDS (swizzled) ----
#pragma unroll
    for (int j = 0; j < 4; ++j)
#pragma unroll
      for (int r = 0; r < 4; ++r) {
        int row = lgrp * 4 + r;
        int col = j * 16 + lrow;
        int ch  = col >> 3;
        Pw[row * 64 + ((ch ^ (row & 7)) << 3) + (col & 7)] = f2bf(sv[j][r]);
      }

    // ---- O += P V ----
#pragma unroll
    for (int ks = 0; ks < 2; ++ks) {
      int ch = ks * 4 + lgrp;
      bf16x8 pa = *(const bf16x8*)&Pw[lrow * 64 + ((ch ^ (lrow & 7)) << 3)];
#pragma unroll
      for (int n = 0; n < 8; ++n) {
        int d = n * 16 + lrow;
        bf16x8 vf = *(const bf16x8*)&Vt[d * 64 + ((ch ^ (d & 7)) << 3)];
        o[n] = __builtin_amdgcn_mfma_f32_16x16x32_bf16(pa, vf, o[n], 0, 0, 0);
      }
    }
    __syncthreads();
  }

  // ---- finalize ----
  const int b = bh >> 4, h = bh & 15;
#pragma unroll
  for (int r = 0; r < 4; ++r) {
    float inv = 1.f / lrun[r];
    int tg = q0 + w * 16 + lgrp * 4 + r;
    unsigned short* dst = attb + ((size_t)(b * Tt + tg) * Cc) + h * DH;
#pragma unroll
    for (int n = 0; n < 8; ++n)
      dst[n * 16 + lrow] = f2bf(o[n][r] * inv);
  }
}

// ---------------------------------------------------------------------------
extern "C" void kernel_launch(void* const* d_in, const int* in_sizes, int n_in,
                              void* d_out, int out_size, void* d_ws, size_t ws_size,
                              hipStream_t stream) {
  const float* x      = (const float*)d_in[0];
  const float* W_attn = (const float*)d_in[1];
  const float* W_proj = (const float*)d_in[2];
  const float* w_std  = (const float*)d_in[3];
  const float* w_rec  = (const float*)d_in[4];
  float* outp = (float*)d_out;

  unsigned short* wsb = (unsigned short*)d_ws;   // 67,108,864 elems = 128 MiB exactly
  unsigned short* xb   = wsb;                 // 8,388,608
  unsigned short* Wab  = wsb + 8388608;       // 12,582,912
  unsigned short* Wpb  = wsb + 20971520;      // 4,194,304
  unsigned short* Qb   = wsb + 25165824;      // 8,388,608
  unsigned short* Kb   = wsb + 33554432;
  unsigned short* Vb   = wsb + 41943040;
  unsigned short* Vtb  = wsb + 50331648;
  unsigned short* attb = wsb + 58720256;

  f2bf_arr<<<1024, 256, 0, stream>>>(x,      xb,  Mm * Cc);
  f2bf_arr<<<1024, 256, 0, stream>>>(W_attn, Wab, FUSED * Cc);
  f2bf_arr<<<1024, 256, 0, stream>>>(W_proj, Wpb, Cc * Cc);

  gemm_bf16<1><<<dim3(FUSED / 128, Mm / 128), dim3(256), 0, stream>>>(
      xb, Wab, nullptr, Qb, Kb, Vb, w_std, w_rec, FUSED, Cc);

  vtrans<<<dim3(Tt / 64, Bb * Hh), dim3(256), 0, stream>>>(Vb, Vtb);

  attn_mfma<<<dim3(Tt / 64, Bb * Hh), dim3(256), 0, stream>>>(Qb, Kb, Vtb, attb);

  gemm_bf16<0><<<dim3(Cc / 128, Mm / 128), dim3(256), 0, stream>>>(
      attb, Wpb, outp, nullptr, nullptr, nullptr, nullptr, nullptr, Cc, Cc);
}

// Round 4
// 432.581 us; speedup vs baseline: 7.5655x; 1.1515x over previous
//
#include <hip/hip_runtime.h>
#include <math.h>

#define Bb 2
#define Tt 2048
#define Cc 2048
#define Hh 16
#define DH 128
#define FUSED 6144
#define Mm 4096
#define QSC 0.08838834764831845f   // 1/sqrt(128)

typedef __bf16 bf16x8 __attribute__((ext_vector_type(8)));
typedef float  f32x4  __attribute__((ext_vector_type(4)));

__device__ __forceinline__ unsigned short f2bf(float f) {
  unsigned int u = __float_as_uint(f);
  u = (u + 0x7fffu + ((u >> 16) & 1u)) >> 16;   // RNE
  return (unsigned short)u;
}

__device__ __forceinline__ void gload16(const void* src, void* lds) {
  __builtin_amdgcn_global_load_lds((const __attribute__((address_space(1))) void*)src,
                                   (__attribute__((address_space(3))) void*)lds, 16, 0, 0);
}

// ---------------------------------------------------------------------------
// fused fp32 -> bf16 convert for x | W_attn | W_proj (dst contiguous in ws)
// ---------------------------------------------------------------------------
#define N1 8388608
#define N2 12582912
#define N3 4194304
__global__ void f2bf_all(const float* __restrict__ s1, const float* __restrict__ s2,
                         const float* __restrict__ s3, unsigned short* __restrict__ dst)
{
  int i = (blockIdx.x * blockDim.x + threadIdx.x) * 4;
  int stride = gridDim.x * blockDim.x * 4;
  for (; i < N1 + N2 + N3; i += stride) {
    const float* src = (i < N1) ? (s1 + i) : (i < N1 + N2) ? (s2 + (i - N1)) : (s3 + (i - N1 - N2));
    float4 v = *(const float4*)src;
    ushort4 o;
    o.x = f2bf(v.x); o.y = f2bf(v.y); o.z = f2bf(v.z); o.w = f2bf(v.w);
    *(ushort4*)&dst[i] = o;
  }
}

// ---------------------------------------------------------------------------
// bf16 MFMA GEMM: C[M,N] = A[M,K] * B[N,K]^T, both bf16 row-major k-contiguous.
// 128x128 tile, BK=64, 4 waves (2x2, each 64x64 out), global_load_lds w=16,
// LDS linear dest + pre-swizzled global source; reads use chunk ^= (row&7).
// MODE 0: fp32 store to out[M,N].  MODE 1: routed bf16 scatter to Q/K/V.
// ---------------------------------------------------------------------------
template <int MODE>
__global__ __launch_bounds__(256)
void gemm_bf16(const unsigned short* __restrict__ A, const unsigned short* __restrict__ Bw,
               float* __restrict__ out,
               unsigned short* __restrict__ Qb, unsigned short* __restrict__ Kb,
               unsigned short* __restrict__ Vb,
               const float* __restrict__ w_std, const float* __restrict__ w_rec,
               int N, int K)
{
  __shared__ unsigned short As[128 * 64];
  __shared__ unsigned short Bs[128 * 64];
  __shared__ float lws[Hh], lwr[Hh];
  __shared__ int   lra[Hh];

  const int tid  = threadIdx.x;
  const int lane = tid & 63;
  const int w    = tid >> 6;
  const int wr   = w >> 1, wc = w & 1;
  const int lrow = lane & 15, lgrp = lane >> 4;
  const int m0 = blockIdx.y * 128;
  const int n0 = blockIdx.x * 128;

  if (MODE == 1 && tid < Hh) {
    float a = w_std[tid]; lws[tid] = sqrtf(a < 1e-8f ? 1e-8f : a);
    float r = w_rec[tid]; lwr[tid] = sqrtf(r < 1e-8f ? 1e-8f : r);
    lra[tid] = (r > 0.1f) ? 1 : 0;
  }

  f32x4 acc[4][4] = {};

  for (int kt = 0; kt < K; kt += 64) {
#pragma unroll
    for (int c = 0; c < 4; ++c) {
      int base16 = (c * 4 + w) * 64;
      int o16 = base16 + lane;
      int rr = o16 >> 3, cc = o16 & 7;
      int csw = (cc ^ (rr & 7)) << 3;
      gload16(A  + (size_t)(m0 + rr) * K + kt + csw, As + base16 * 8);
      gload16(Bw + (size_t)(n0 + rr) * K + kt + csw, Bs + base16 * 8);
    }
    __syncthreads();

#pragma unroll
    for (int s = 0; s < 2; ++s) {
      bf16x8 af[4], bfr[4];
#pragma unroll
      for (int i = 0; i < 4; ++i) {
        int row = wr * 64 + i * 16 + lrow;
        int ch  = s * 4 + lgrp;
        af[i]  = *(const bf16x8*)&As[row * 64 + ((ch ^ (row & 7)) << 3)];
        int col = wc * 64 + i * 16 + lrow;
        bfr[i] = *(const bf16x8*)&Bs[col * 64 + ((ch ^ (col & 7)) << 3)];
      }
#pragma unroll
      for (int i = 0; i < 4; ++i)
#pragma unroll
        for (int j = 0; j < 4; ++j)
          acc[i][j] = __builtin_amdgcn_mfma_f32_16x16x32_bf16(af[i], bfr[j], acc[i][j], 0, 0, 0);
    }
    __syncthreads();
  }

  if (MODE == 0) {
#pragma unroll
    for (int i = 0; i < 4; ++i)
#pragma unroll
      for (int r = 0; r < 4; ++r) {
        int m = m0 + wr * 64 + i * 16 + lgrp * 4 + r;
#pragma unroll
        for (int j = 0; j < 4; ++j) {
          int n = n0 + wc * 64 + j * 16 + lrow;
          out[(size_t)m * N + n] = acc[i][j][r];
        }
      }
  } else {
#pragma unroll
    for (int i = 0; i < 4; ++i)
#pragma unroll
      for (int r = 0; r < 4; ++r) {
        int m = m0 + wr * 64 + i * 16 + lgrp * 4 + r;
        int b = m >> 11, t = m & 2047;
#pragma unroll
        for (int j = 0; j < 4; ++j) {
          int f = n0 + wc * 64 + j * 16 + lrow;
          float v = acc[i][j][r];
          unsigned short* dst; int h, d; float sc;
          if (f < 1920)      { h = f / 120; d = f - h * 120; dst = Qb; sc = lws[h] * QSC; }
          else if (f < 3840) { int g = f - 1920; h = g / 120; d = g - h * 120; dst = Kb; sc = lws[h]; }
          else if (f < 5888) { int g = f - 3840; h = g >> 7; d = g & 127; dst = Vb; sc = 1.f; }
          else if (f < 6016) { int g = f - 5888; h = g >> 3; d = 120 + (g & 7);
                               if (lra[h]) { dst = Kb; sc = lwr[h]; }
                               else        { dst = Qb; sc = lws[h] * QSC; } }
          else               { int g = f - 6016; h = g >> 3; d = 120 + (g & 7);
                               if (lra[h]) { dst = Qb; sc = lwr[h] * QSC; }
                               else        { dst = Kb; sc = lws[h]; } }
          dst[((((size_t)b * Hh + h) * Tt + t) << 7) + d] = f2bf(v * sc);
        }
      }
  }
}

// ---------------------------------------------------------------------------
// V[bh][t][d] -> Vt[bh][d][t] (bf16)
// ---------------------------------------------------------------------------
__global__ __launch_bounds__(256)
void vtrans(const unsigned short* __restrict__ Vb, unsigned short* __restrict__ Vtb)
{
  __shared__ unsigned short Vs[64 * 128];
  const int tid = threadIdx.x;
  const int bh = blockIdx.y, t0 = blockIdx.x * 64;
  const unsigned short* src = Vb + ((size_t)bh * Tt + t0) * DH;
#pragma unroll
  for (int c = 0; c < 4; ++c) {
    int u = c * 256 + tid;
    int row = u >> 4, ch = u & 15;
    *(uint4*)&Vs[row * 128 + ch * 8] = *(const uint4*)&src[(size_t)row * DH + ch * 8];
  }
  __syncthreads();
  unsigned short* dstb = Vtb + (size_t)bh * DH * Tt + t0;
#pragma unroll
  for (int c = 0; c < 4; ++c) {
    int u = c * 256 + tid;
    int d = u & 127, tc = u >> 7;
    unsigned short tmp[8];
#pragma unroll
    for (int j = 0; j < 8; ++j) tmp[j] = Vs[(tc * 8 + j) * 128 + d];
    *(uint4*)&dstb[(size_t)d * Tt + tc * 8] = *(uint4*)tmp;
  }
}

// ---------------------------------------------------------------------------
// MFMA flash attention, pair-balanced.
// Grid: 256 blocks (bid -> {pair 0..7, bh 0..31}, bid%8 == bh%8 for XCD/L2
// locality). 512 threads = 8 waves x 16 q-rows. Each block runs two q-phases
// (qt and 15-qt, 128 rows each) -> uniform 34 kv-tiles of 64 per block.
// K/V double-buffered in 80KB dynamic LDS; prefetch of tile t+1 issued before
// compute of tile t. Q-fragments loaded global->reg directly.
// ---------------------------------------------------------------------------
__global__ __launch_bounds__(512)
void attn_mfma(const unsigned short* __restrict__ Qb, const unsigned short* __restrict__ Kb,
               const unsigned short* __restrict__ Vtb, unsigned short* __restrict__ attb)
{
  extern __shared__ unsigned short smem[];
  unsigned short* KT = smem;               // 2 x [64][128]
  unsigned short* VT = smem + 2 * 8192;    // 2 x [128][64]
  unsigned short* PB = smem + 4 * 8192;    // 8 waves x [16][64]

  const int tid = threadIdx.x, lane = tid & 63, wav = tid >> 6;
  const int lrow = lane & 15, lgrp = lane >> 4;
  const int bid = blockIdx.x;
  const int xs  = bid & 7;
  const int rem = bid >> 3;
  const int bh  = xs + ((rem & 3) << 3);   // bh%8 == bid%8 -> same XCD per bh
  const int pr  = rem >> 2;                // pair id 0..7

  const unsigned short* Qh = Qb  + (size_t)bh * Tt * DH;
  const unsigned short* Kh = Kb  + (size_t)bh * Tt * DH;
  const unsigned short* Vh = Vtb + (size_t)bh * DH * Tt;
  const int b = bh >> 4, h = bh & 15;

  unsigned short* Pw = PB + wav * 1024;    // per-wave P [16][64]

  auto stage = [&](int buf, int kv0) {
    unsigned short* Kd = KT + buf * 8192;
    unsigned short* Vd = VT + buf * 8192;
#pragma unroll
    for (int s = 0; s < 2; ++s) {
      int base16 = s * 512 + wav * 64;     // wave-uniform 16B-chunk base
      int o16 = base16 + lane;
      { int rr = o16 >> 4, cc = o16 & 15;  // K: 64 rows x 16 chunks
        gload16(Kh + (size_t)(kv0 + rr) * DH + ((cc ^ (rr & 7)) << 3), Kd + base16 * 8); }
      { int rr = o16 >> 3, cc = o16 & 7;   // Vt: 128 rows x 8 chunks
        gload16(Vh + (size_t)rr * Tt + kv0 + ((cc ^ (rr & 7)) << 3), Vd + base16 * 8); }
    }
  };

  int cur = 0;
  stage(0, 0);

  for (int ph = 0; ph < 2; ++ph) {
    const int qt = ph ? (15 - pr) : pr;
    const int q0 = qt * 128;
    const int nt = 2 * (qt + 1);

    // Q fragments direct from global (one-time per phase)
    bf16x8 qf[4];
#pragma unroll
    for (int ks = 0; ks < 4; ++ks)
      qf[ks] = *(const bf16x8*)(Qh + (size_t)(q0 + wav * 16 + lrow) * DH + ks * 32 + lgrp * 8);

    f32x4 o[8] = {};
    float mrun[4], lrun[4];
#pragma unroll
    for (int r = 0; r < 4; ++r) { mrun[r] = -INFINITY; lrun[r] = 0.f; }

    for (int t = 0; t < nt; ++t) {
      const int kv0 = t * 64;
      __syncthreads();                     // tile t staged; prev reads done
      bool more = (t + 1 < nt);
      if (more)            stage(cur ^ 1, kv0 + 64);
      else if (ph == 0)    stage(cur ^ 1, 0);     // prefetch tile 0 of phase B

      const unsigned short* Kc = KT + cur * 8192;
      const unsigned short* Vc = VT + cur * 8192;

      // ---- S = Q K^T (16 q-rows x 64 kv per wave) ----
      f32x4 sv[4] = {};
#pragma unroll
      for (int ks = 0; ks < 4; ++ks)
#pragma unroll
        for (int j = 0; j < 4; ++j) {
          int krow = j * 16 + lrow;
          int ch   = ks * 4 + lgrp;
          bf16x8 kf = *(const bf16x8*)&Kc[krow * 128 + ((ch ^ (krow & 7)) << 3)];
          sv[j] = __builtin_amdgcn_mfma_f32_16x16x32_bf16(qf[ks], kf, sv[j], 0, 0, 0);
        }

      // ---- online softmax ----
      const bool domask = (kv0 >= q0);
      float sc[4];
#pragma unroll
      for (int r = 0; r < 4; ++r) {
        if (domask) {
          int qrow = q0 + wav * 16 + lgrp * 4 + r;
#pragma unroll
          for (int j = 0; j < 4; ++j) {
            int kv = kv0 + j * 16 + lrow;
            if (kv > qrow) sv[j][r] = -INFINITY;
          }
        }
        float m_ = fmaxf(fmaxf(sv[0][r], sv[1][r]), fmaxf(sv[2][r], sv[3][r]));
        m_ = fmaxf(m_, __shfl_xor(m_, 1));
        m_ = fmaxf(m_, __shfl_xor(m_, 2));
        m_ = fmaxf(m_, __shfl_xor(m_, 4));
        m_ = fmaxf(m_, __shfl_xor(m_, 8));
        float mn = fmaxf(mrun[r], m_);
        sc[r] = __expf(mrun[r] - mn);
        mrun[r] = mn;
        float rs = 0.f;
#pragma unroll
        for (int j = 0; j < 4; ++j) {
          float p = __expf(sv[j][r] - mn);
          sv[j][r] = p;
          rs += p;
        }
        rs += __shfl_xor(rs, 1);
        rs += __shfl_xor(rs, 2);
        rs += __shfl_xor(rs, 4);
        rs += __shfl_xor(rs, 8);
        lrun[r] = lrun[r] * sc[r] + rs;
      }

      // ---- rescale O ----
#pragma unroll
      for (int n = 0; n < 8; ++n)
#pragma unroll
        for (int r = 0; r < 4; ++r) o[n][r] *= sc[r];

      // ---- P -> bf16 -> per-wave LDS (swizzled) ----
#pragma unroll
      for (int j = 0; j < 4; ++j)
#pragma unroll
        for (int r = 0; r < 4; ++r) {
          int row = lgrp * 4 + r;
          int col = j * 16 + lrow;
          int ch  = col >> 3;
          Pw[row * 64 + ((ch ^ (row & 7)) << 3) + (col & 7)] = f2bf(sv[j][r]);
        }

      // ---- O += P V ----
#pragma unroll
      for (int ks = 0; ks < 2; ++ks) {
        int ch = ks * 4 + lgrp;
        bf16x8 pa = *(const bf16x8*)&Pw[lrow * 64 + ((ch ^ (lrow & 7)) << 3)];
#pragma unroll
        for (int n = 0; n < 8; ++n) {
          int d = n * 16 + lrow;
          bf16x8 vf = *(const bf16x8*)&Vc[d * 64 + ((ch ^ (d & 7)) << 3)];
          o[n] = __builtin_amdgcn_mfma_f32_16x16x32_bf16(pa, vf, o[n], 0, 0, 0);
        }
      }
      cur ^= 1;
    }

    // ---- finalize phase ----
#pragma unroll
    for (int r = 0; r < 4; ++r) {
      float inv = 1.f / lrun[r];
      int tg = q0 + wav * 16 + lgrp * 4 + r;
      unsigned short* dst = attb + ((size_t)(b * Tt + tg) * Cc) + h * DH;
#pragma unroll
      for (int n = 0; n < 8; ++n)
        dst[n * 16 + lrow] = f2bf(o[n][r] * inv);
    }
  }
}

// ---------------------------------------------------------------------------
extern "C" void kernel_launch(void* const* d_in, const int* in_sizes, int n_in,
                              void* d_out, int out_size, void* d_ws, size_t ws_size,
                              hipStream_t stream) {
  const float* x      = (const float*)d_in[0];
  const float* W_attn = (const float*)d_in[1];
  const float* W_proj = (const float*)d_in[2];
  const float* w_std  = (const float*)d_in[3];
  const float* w_rec  = (const float*)d_in[4];
  float* outp = (float*)d_out;

  unsigned short* wsb = (unsigned short*)d_ws;   // 67,108,864 bf16 elems = 128 MiB
  unsigned short* xb   = wsb;                 // 8,388,608
  unsigned short* Wab  = wsb + 8388608;       // 12,582,912
  unsigned short* Wpb  = wsb + 20971520;      // 4,194,304
  unsigned short* Qb   = wsb + 25165824;      // 8,388,608
  unsigned short* Kb   = wsb + 33554432;
  unsigned short* Vb   = wsb + 41943040;
  unsigned short* Vtb  = wsb + 50331648;
  unsigned short* attb = wsb + 58720256;

  f2bf_all<<<2048, 256, 0, stream>>>(x, W_attn, W_proj, wsb);

  gemm_bf16<1><<<dim3(FUSED / 128, Mm / 128), dim3(256), 0, stream>>>(
      xb, Wab, nullptr, Qb, Kb, Vb, w_std, w_rec, FUSED, Cc);

  vtrans<<<dim3(Tt / 64, Bb * Hh), dim3(256), 0, stream>>>(Vb, Vtb);

  attn_mfma<<<dim3(256), dim3(512), 81920, stream>>>(Qb, Kb, Vtb, attb);

  gemm_bf16<0><<<dim3(Cc / 128, Mm / 128), dim3(256), 0, stream>>>(
      attb, Wpb, outp, nullptr, nullptr, nullptr, nullptr, nullptr, Cc, Cc);
}

// Round 5
// 416.065 us; speedup vs baseline: 7.8659x; 1.0397x over previous
//
#include <hip/hip_runtime.h>
#include <math.h>

#define Bb 2
#define Tt 2048
#define Cc 2048
#define Hh 16
#define DH 128
#define FUSED 6144
#define Mm 4096
#define QSC 0.08838834764831845f   // 1/sqrt(128)

typedef __bf16 bf16x8 __attribute__((ext_vector_type(8)));
typedef float  f32x4  __attribute__((ext_vector_type(4)));

__device__ __forceinline__ unsigned short f2bf(float f) {
  unsigned int u = __float_as_uint(f);
  u = (u + 0x7fffu + ((u >> 16) & 1u)) >> 16;   // RNE
  return (unsigned short)u;
}

__device__ __forceinline__ void gload16(const void* src, void* lds) {
  __builtin_amdgcn_global_load_lds((const __attribute__((address_space(1))) void*)src,
                                   (__attribute__((address_space(3))) void*)lds, 16, 0, 0);
}

// ---------------------------------------------------------------------------
// fused fp32 -> bf16 convert for x | W_attn | W_proj (dst contiguous in ws)
// ---------------------------------------------------------------------------
#define N1 8388608
#define N2 12582912
#define N3 4194304
__global__ void f2bf_all(const float* __restrict__ s1, const float* __restrict__ s2,
                         const float* __restrict__ s3, unsigned short* __restrict__ dst)
{
  int i = (blockIdx.x * blockDim.x + threadIdx.x) * 4;
  int stride = gridDim.x * blockDim.x * 4;
  for (; i < N1 + N2 + N3; i += stride) {
    const float* src = (i < N1) ? (s1 + i) : (i < N1 + N2) ? (s2 + (i - N1)) : (s3 + (i - N1 - N2));
    float4 v = *(const float4*)src;
    ushort4 o;
    o.x = f2bf(v.x); o.y = f2bf(v.y); o.z = f2bf(v.z); o.w = f2bf(v.w);
    *(ushort4*)&dst[i] = o;
  }
}

// ---------------------------------------------------------------------------
// bf16 MFMA GEMM v2: C[M,N] = A[M,K] * B[N,K]^T, both bf16 k-contiguous.
// 128x256 tile, BK=64, 512 threads = 8 waves (2x4), wave out 64x64.
// Double-buffered LDS (96KB dynamic): stage(t+1) issued at loop top, compute
// tile t, ONE __syncthreads per K-tile (implicit vmcnt drain joins all waves'
// prefetch arrivals; loads were issued a full tile earlier). setprio around
// MFMA clusters. Reads/writes use the proven chunk^=(row&7) swizzle
// (pre-swizzled global source, linear LDS dest) -> 0 bank conflicts.
// MODE 0: fp32 store to out[M,N].  MODE 1: routed bf16 scatter to Q/K/V.
// ---------------------------------------------------------------------------
template <int MODE>
__global__ __launch_bounds__(512)
void gemm_bf16(const unsigned short* __restrict__ A, const unsigned short* __restrict__ Bw,
               float* __restrict__ out,
               unsigned short* __restrict__ Qb, unsigned short* __restrict__ Kb,
               unsigned short* __restrict__ Vb,
               const float* __restrict__ w_std, const float* __restrict__ w_rec,
               int N, int K)
{
  extern __shared__ unsigned short sm[];    // As[2][128*64] | Bs[2][256*64]
  __shared__ float lws[Hh], lwr[Hh];
  __shared__ int   lra[Hh];

  const int tid  = threadIdx.x;
  const int lane = tid & 63;
  const int wav  = tid >> 6;
  const int wm   = wav >> 2, wn = wav & 3;   // wave grid 2x4
  const int lrow = lane & 15, lgrp = lane >> 4;
  const int m0 = blockIdx.y * 128;
  const int n0 = blockIdx.x * 256;

  if (MODE == 1 && tid < Hh) {
    float a = w_std[tid]; lws[tid] = sqrtf(a < 1e-8f ? 1e-8f : a);
    float r = w_rec[tid]; lwr[tid] = sqrtf(r < 1e-8f ? 1e-8f : r);
    lra[tid] = (r > 0.1f) ? 1 : 0;
  }

  auto stage = [&](int buf, int kt) {
    unsigned short* Ad = sm + buf * 8192;
    unsigned short* Bd = sm + 16384 + buf * 16384;
#pragma unroll
    for (int s = 0; s < 2; ++s) {            // A: 128 rows x 8 chunks
      int base16 = s * 512 + wav * 64;
      int o16 = base16 + lane;
      int rr = o16 >> 3, cc = o16 & 7;
      gload16(A + (size_t)(m0 + rr) * K + kt + ((cc ^ (rr & 7)) << 3), Ad + base16 * 8);
    }
#pragma unroll
    for (int s = 0; s < 4; ++s) {            // B: 256 rows x 8 chunks
      int base16 = s * 512 + wav * 64;
      int o16 = base16 + lane;
      int rr = o16 >> 3, cc = o16 & 7;
      gload16(Bw + (size_t)(n0 + rr) * K + kt + ((cc ^ (rr & 7)) << 3), Bd + base16 * 8);
    }
  };

  stage(0, 0);
  __syncthreads();

  f32x4 acc[4][4] = {};
  const int NT = K >> 6;

  for (int t = 0; t < NT; ++t) {
    const int cur = t & 1;
    if (t + 1 < NT) stage(cur ^ 1, (t + 1) << 6);   // prefetch BEFORE compute

    const unsigned short* Ac = sm + cur * 8192;
    const unsigned short* Bc = sm + 16384 + cur * 16384;
#pragma unroll
    for (int s = 0; s < 2; ++s) {
      bf16x8 af[4], bfr[4];
#pragma unroll
      for (int i = 0; i < 4; ++i) {
        int row = wm * 64 + i * 16 + lrow;
        int ch  = s * 4 + lgrp;
        af[i]  = *(const bf16x8*)&Ac[row * 64 + ((ch ^ (row & 7)) << 3)];
        int col = wn * 64 + i * 16 + lrow;
        bfr[i] = *(const bf16x8*)&Bc[col * 64 + ((ch ^ (col & 7)) << 3)];
      }
      __builtin_amdgcn_s_setprio(1);
#pragma unroll
      for (int i = 0; i < 4; ++i)
#pragma unroll
        for (int j = 0; j < 4; ++j)
          acc[i][j] = __builtin_amdgcn_mfma_f32_16x16x32_bf16(af[i], bfr[j], acc[i][j], 0, 0, 0);
      __builtin_amdgcn_s_setprio(0);
    }
    __syncthreads();   // drains this wave's prefetch (issued a full tile ago) + joins
  }

  if (MODE == 0) {
#pragma unroll
    for (int i = 0; i < 4; ++i)
#pragma unroll
      for (int r = 0; r < 4; ++r) {
        int m = m0 + wm * 64 + i * 16 + lgrp * 4 + r;
#pragma unroll
        for (int j = 0; j < 4; ++j) {
          int n = n0 + wn * 64 + j * 16 + lrow;
          out[(size_t)m * N + n] = acc[i][j][r];
        }
      }
  } else {
#pragma unroll
    for (int i = 0; i < 4; ++i)
#pragma unroll
      for (int r = 0; r < 4; ++r) {
        int m = m0 + wm * 64 + i * 16 + lgrp * 4 + r;
        int b = m >> 11, t = m & 2047;
#pragma unroll
        for (int j = 0; j < 4; ++j) {
          int f = n0 + wn * 64 + j * 16 + lrow;
          float v = acc[i][j][r];
          unsigned short* dst; int h, d; float sc;
          if (f < 1920)      { h = f / 120; d = f - h * 120; dst = Qb; sc = lws[h] * QSC; }
          else if (f < 3840) { int g = f - 1920; h = g / 120; d = g - h * 120; dst = Kb; sc = lws[h]; }
          else if (f < 5888) { int g = f - 3840; h = g >> 7; d = g & 127; dst = Vb; sc = 1.f; }
          else if (f < 6016) { int g = f - 5888; h = g >> 3; d = 120 + (g & 7);
                               if (lra[h]) { dst = Kb; sc = lwr[h]; }
                               else        { dst = Qb; sc = lws[h] * QSC; } }
          else               { int g = f - 6016; h = g >> 3; d = 120 + (g & 7);
                               if (lra[h]) { dst = Qb; sc = lwr[h] * QSC; }
                               else        { dst = Kb; sc = lws[h]; } }
          dst[((((size_t)b * Hh + h) * Tt + t) << 7) + d] = f2bf(v * sc);
        }
      }
  }
}

// ---------------------------------------------------------------------------
// V[bh][t][d] -> Vt[bh][d][t] (bf16)  (unchanged)
// ---------------------------------------------------------------------------
__global__ __launch_bounds__(256)
void vtrans(const unsigned short* __restrict__ Vb, unsigned short* __restrict__ Vtb)
{
  __shared__ unsigned short Vs[64 * 128];
  const int tid = threadIdx.x;
  const int bh = blockIdx.y, t0 = blockIdx.x * 64;
  const unsigned short* src = Vb + ((size_t)bh * Tt + t0) * DH;
#pragma unroll
  for (int c = 0; c < 4; ++c) {
    int u = c * 256 + tid;
    int row = u >> 4, ch = u & 15;
    *(uint4*)&Vs[row * 128 + ch * 8] = *(const uint4*)&src[(size_t)row * DH + ch * 8];
  }
  __syncthreads();
  unsigned short* dstb = Vtb + (size_t)bh * DH * Tt + t0;
#pragma unroll
  for (int c = 0; c < 4; ++c) {
    int u = c * 256 + tid;
    int d = u & 127, tc = u >> 7;
    unsigned short tmp[8];
#pragma unroll
    for (int j = 0; j < 8; ++j) tmp[j] = Vs[(tc * 8 + j) * 128 + d];
    *(uint4*)&dstb[(size_t)d * Tt + tc * 8] = *(uint4*)tmp;
  }
}

// ---------------------------------------------------------------------------
// MFMA flash attention, pair-balanced (unchanged from round 4).
// ---------------------------------------------------------------------------
__global__ __launch_bounds__(512)
void attn_mfma(const unsigned short* __restrict__ Qb, const unsigned short* __restrict__ Kb,
               const unsigned short* __restrict__ Vtb, unsigned short* __restrict__ attb)
{
  extern __shared__ unsigned short smem[];
  unsigned short* KT = smem;               // 2 x [64][128]
  unsigned short* VT = smem + 2 * 8192;    // 2 x [128][64]
  unsigned short* PB = smem + 4 * 8192;    // 8 waves x [16][64]

  const int tid = threadIdx.x, lane = tid & 63, wav = tid >> 6;
  const int lrow = lane & 15, lgrp = lane >> 4;
  const int bid = blockIdx.x;
  const int xs  = bid & 7;
  const int rem = bid >> 3;
  const int bh  = xs + ((rem & 3) << 3);   // bh%8 == bid%8 -> same XCD per bh
  const int pr  = rem >> 2;                // pair id 0..7

  const unsigned short* Qh = Qb  + (size_t)bh * Tt * DH;
  const unsigned short* Kh = Kb  + (size_t)bh * Tt * DH;
  const unsigned short* Vh = Vtb + (size_t)bh * DH * Tt;
  const int b = bh >> 4, h = bh & 15;

  unsigned short* Pw = PB + wav * 1024;    // per-wave P [16][64]

  auto stage = [&](int buf, int kv0) {
    unsigned short* Kd = KT + buf * 8192;
    unsigned short* Vd = VT + buf * 8192;
#pragma unroll
    for (int s = 0; s < 2; ++s) {
      int base16 = s * 512 + wav * 64;
      int o16 = base16 + lane;
      { int rr = o16 >> 4, cc = o16 & 15;
        gload16(Kh + (size_t)(kv0 + rr) * DH + ((cc ^ (rr & 7)) << 3), Kd + base16 * 8); }
      { int rr = o16 >> 3, cc = o16 & 7;
        gload16(Vh + (size_t)rr * Tt + kv0 + ((cc ^ (rr & 7)) << 3), Vd + base16 * 8); }
    }
  };

  int cur = 0;
  stage(0, 0);

  for (int ph = 0; ph < 2; ++ph) {
    const int qt = ph ? (15 - pr) : pr;
    const int q0 = qt * 128;
    const int nt = 2 * (qt + 1);

    bf16x8 qf[4];
#pragma unroll
    for (int ks = 0; ks < 4; ++ks)
      qf[ks] = *(const bf16x8*)(Qh + (size_t)(q0 + wav * 16 + lrow) * DH + ks * 32 + lgrp * 8);

    f32x4 o[8] = {};
    float mrun[4], lrun[4];
#pragma unroll
    for (int r = 0; r < 4; ++r) { mrun[r] = -INFINITY; lrun[r] = 0.f; }

    for (int t = 0; t < nt; ++t) {
      const int kv0 = t * 64;
      __syncthreads();
      bool more = (t + 1 < nt);
      if (more)            stage(cur ^ 1, kv0 + 64);
      else if (ph == 0)    stage(cur ^ 1, 0);

      const unsigned short* Kc = KT + cur * 8192;
      const unsigned short* Vc = VT + cur * 8192;

      f32x4 sv[4] = {};
#pragma unroll
      for (int ks = 0; ks < 4; ++ks)
#pragma unroll
        for (int j = 0; j < 4; ++j) {
          int krow = j * 16 + lrow;
          int ch   = ks * 4 + lgrp;
          bf16x8 kf = *(const bf16x8*)&Kc[krow * 128 + ((ch ^ (krow & 7)) << 3)];
          sv[j] = __builtin_amdgcn_mfma_f32_16x16x32_bf16(qf[ks], kf, sv[j], 0, 0, 0);
        }

      const bool domask = (kv0 >= q0);
      float sc[4];
#pragma unroll
      for (int r = 0; r < 4; ++r) {
        if (domask) {
          int qrow = q0 + wav * 16 + lgrp * 4 + r;
#pragma unroll
          for (int j = 0; j < 4; ++j) {
            int kv = kv0 + j * 16 + lrow;
            if (kv > qrow) sv[j][r] = -INFINITY;
          }
        }
        float m_ = fmaxf(fmaxf(sv[0][r], sv[1][r]), fmaxf(sv[2][r], sv[3][r]));
        m_ = fmaxf(m_, __shfl_xor(m_, 1));
        m_ = fmaxf(m_, __shfl_xor(m_, 2));
        m_ = fmaxf(m_, __shfl_xor(m_, 4));
        m_ = fmaxf(m_, __shfl_xor(m_, 8));
        float mn = fmaxf(mrun[r], m_);
        sc[r] = __expf(mrun[r] - mn);
        mrun[r] = mn;
        float rs = 0.f;
#pragma unroll
        for (int j = 0; j < 4; ++j) {
          float p = __expf(sv[j][r] - mn);
          sv[j][r] = p;
          rs += p;
        }
        rs += __shfl_xor(rs, 1);
        rs += __shfl_xor(rs, 2);
        rs += __shfl_xor(rs, 4);
        rs += __shfl_xor(rs, 8);
        lrun[r] = lrun[r] * sc[r] + rs;
      }

#pragma unroll
      for (int n = 0; n < 8; ++n)
#pragma unroll
        for (int r = 0; r < 4; ++r) o[n][r] *= sc[r];

#pragma unroll
      for (int j = 0; j < 4; ++j)
#pragma unroll
        for (int r = 0; r < 4; ++r) {
          int row = lgrp * 4 + r;
          int col = j * 16 + lrow;
          int ch  = col >> 3;
          Pw[row * 64 + ((ch ^ (row & 7)) << 3) + (col & 7)] = f2bf(sv[j][r]);
        }

#pragma unroll
      for (int ks = 0; ks < 2; ++ks) {
        int ch = ks * 4 + lgrp;
        bf16x8 pa = *(const bf16x8*)&Pw[lrow * 64 + ((ch ^ (lrow & 7)) << 3)];
#pragma unroll
        for (int n = 0; n < 8; ++n) {
          int d = n * 16 + lrow;
          bf16x8 vf = *(const bf16x8*)&Vc[d * 64 + ((ch ^ (d & 7)) << 3)];
          o[n] = __builtin_amdgcn_mfma_f32_16x16x32_bf16(pa, vf, o[n], 0, 0, 0);
        }
      }
      cur ^= 1;
    }

#pragma unroll
    for (int r = 0; r < 4; ++r) {
      float inv = 1.f / lrun[r];
      int tg = q0 + wav * 16 + lgrp * 4 + r;
      unsigned short* dst = attb + ((size_t)(b * Tt + tg) * Cc) + h * DH;
#pragma unroll
      for (int n = 0; n < 8; ++n)
        dst[n * 16 + lrow] = f2bf(o[n][r] * inv);
    }
  }
}

// ---------------------------------------------------------------------------
extern "C" void kernel_launch(void* const* d_in, const int* in_sizes, int n_in,
                              void* d_out, int out_size, void* d_ws, size_t ws_size,
                              hipStream_t stream) {
  const float* x      = (const float*)d_in[0];
  const float* W_attn = (const float*)d_in[1];
  const float* W_proj = (const float*)d_in[2];
  const float* w_std  = (const float*)d_in[3];
  const float* w_rec  = (const float*)d_in[4];
  float* outp = (float*)d_out;

  unsigned short* wsb = (unsigned short*)d_ws;   // 67,108,864 bf16 elems = 128 MiB
  unsigned short* xb   = wsb;                 // 8,388,608
  unsigned short* Wab  = wsb + 8388608;       // 12,582,912
  unsigned short* Wpb  = wsb + 20971520;      // 4,194,304
  unsigned short* Qb   = wsb + 25165824;      // 8,388,608
  unsigned short* Kb   = wsb + 33554432;
  unsigned short* Vb   = wsb + 41943040;
  unsigned short* Vtb  = wsb + 50331648;
  unsigned short* attb = wsb + 58720256;

  f2bf_all<<<2048, 256, 0, stream>>>(x, W_attn, W_proj, wsb);

  // 128x256 tile: grid (N/256, M/128); 96KB dynamic LDS
  gemm_bf16<1><<<dim3(FUSED / 256, Mm / 128), dim3(512), 98304, stream>>>(
      xb, Wab, nullptr, Qb, Kb, Vb, w_std, w_rec, FUSED, Cc);

  vtrans<<<dim3(Tt / 64, Bb * Hh), dim3(256), 0, stream>>>(Vb, Vtb);

  attn_mfma<<<dim3(256), dim3(512), 81920, stream>>>(Qb, Kb, Vtb, attb);

  gemm_bf16<0><<<dim3(Cc / 256, Mm / 128), dim3(512), 98304, stream>>>(
      attb, Wpb, outp, nullptr, nullptr, nullptr, nullptr, nullptr, Cc, Cc);
}

// Round 6
// 408.419 us; speedup vs baseline: 8.0131x; 1.0187x over previous
//
#include <hip/hip_runtime.h>
#include <math.h>

#define Bb 2
#define Tt 2048
#define Cc 2048
#define Hh 16
#define DH 128
#define FUSED 6144
#define Mm 4096
#define QSC 0.08838834764831845f   // 1/sqrt(128)

typedef __bf16 bf16x8 __attribute__((ext_vector_type(8)));
typedef float  f32x4  __attribute__((ext_vector_type(4)));

__device__ __forceinline__ unsigned short f2bf(float f) {
  unsigned int u = __float_as_uint(f);
  u = (u + 0x7fffu + ((u >> 16) & 1u)) >> 16;   // RNE
  return (unsigned short)u;
}

__device__ __forceinline__ void gload16(const void* src, void* lds) {
  __builtin_amdgcn_global_load_lds((const __attribute__((address_space(1))) void*)src,
                                   (__attribute__((address_space(3))) void*)lds, 16, 0, 0);
}

// ---------------------------------------------------------------------------
// fused fp32 -> bf16 convert for x | W_attn | W_proj (dst contiguous in ws)
// ---------------------------------------------------------------------------
#define N1 8388608
#define N2 12582912
#define N3 4194304
__global__ void f2bf_all(const float* __restrict__ s1, const float* __restrict__ s2,
                         const float* __restrict__ s3, unsigned short* __restrict__ dst)
{
  int i = (blockIdx.x * blockDim.x + threadIdx.x) * 4;
  int stride = gridDim.x * blockDim.x * 4;
  for (; i < N1 + N2 + N3; i += stride) {
    const float* src = (i < N1) ? (s1 + i) : (i < N1 + N2) ? (s2 + (i - N1)) : (s3 + (i - N1 - N2));
    float4 v = *(const float4*)src;
    ushort4 o;
    o.x = f2bf(v.x); o.y = f2bf(v.y); o.z = f2bf(v.z); o.w = f2bf(v.w);
    *(ushort4*)&dst[i] = o;
  }
}

// ---------------------------------------------------------------------------
// gemm1_pipe: fused = x @ W_attn^T with routed Q/K/V scatter epilogue.
// BM=128, BN=256, BK=32. 512 thr = 8 waves (1M x 8N), per-wave out 128x32.
// 3 LDS buffers (72KB -> 2 blocks/CU). Counted-vmcnt pipeline:
//   top of tile t: issue stage3(t+2) -> buf (t+2)%3  [readers ended at t-1 barrier]
//   compute tile t (16 MFMA/wave)
//   boundary: s_waitcnt vmcnt(3)  [retires tile t+1's B,B,A; keeps t+2 in flight]
//             s_barrier  (memory-clobber fenced both sides)
// Swizzle: chunk c ^= (r&3)^((r>>2)&3), pre-swizzled global source, linear LDS
// dest, same XOR on read -> 2-way (free) bank access.
// ---------------------------------------------------------------------------
__global__ __launch_bounds__(512, 4)
void gemm1_pipe(const unsigned short* __restrict__ A, const unsigned short* __restrict__ Bw,
                unsigned short* __restrict__ Qb, unsigned short* __restrict__ Kb,
                unsigned short* __restrict__ Vb,
                const float* __restrict__ w_std, const float* __restrict__ w_rec,
                int N, int K)
{
  extern __shared__ unsigned short sm[];   // As[3][4096] | Bs[3][8192]  (72KB)
  __shared__ float lws[Hh], lwr[Hh];
  __shared__ int   lra[Hh];

  const int tid  = threadIdx.x;
  const int lane = tid & 63;
  const int wav  = tid >> 6;               // 0..7 = wn (1M x 8N)
  const int lrow = lane & 15, lgrp = lane >> 4;
  const int m0 = blockIdx.y * 128;
  const int n0 = blockIdx.x * 256;

  if (tid < Hh) {
    float a = w_std[tid]; lws[tid] = sqrtf(a < 1e-8f ? 1e-8f : a);
    float r = w_rec[tid]; lwr[tid] = sqrtf(r < 1e-8f ? 1e-8f : r);
    lra[tid] = (r > 0.1f) ? 1 : 0;
  }

  auto stage3 = [&](int buf, int kt) {     // issue order: B,B,A (3 vmem instrs)
    unsigned short* Bd = sm + 12288 + buf * 8192;
    unsigned short* Ad = sm + buf * 4096;
#pragma unroll
    for (int s = 0; s < 2; ++s) {          // B: 256 rows x 4 chunks
      int base16 = (s * 8 + wav) * 64;
      int o16 = base16 + lane;
      int r = o16 >> 2, c = o16 & 3;
      int cs = c ^ (r & 3) ^ ((r >> 2) & 3);
      gload16(Bw + (size_t)(n0 + r) * K + kt + cs * 8, Bd + base16 * 8);
    }
    {                                      // A: 128 rows x 4 chunks
      int base16 = wav * 64;
      int o16 = base16 + lane;
      int r = o16 >> 2, c = o16 & 3;
      int cs = c ^ (r & 3) ^ ((r >> 2) & 3);
      gload16(A + (size_t)(m0 + r) * K + kt + cs * 8, Ad + base16 * 8);
    }
  };

  f32x4 acc[8][2] = {};
  const int NT = K >> 5;                   // 64 K-tiles

  // prologue: tiles 0 and 1 staged; wait tile 0 complete (tile 1 in flight)
  stage3(0, 0);
  stage3(1, 32);
  asm volatile("s_waitcnt vmcnt(3)" ::: "memory");
  __builtin_amdgcn_s_barrier();
  asm volatile("" ::: "memory");

  for (int t = 0; t < NT; ++t) {
    const int p = t % 3;
    if (t + 2 < NT) stage3((t + 2) % 3, (t + 2) << 5);

    const unsigned short* Ac = sm + p * 4096;
    const unsigned short* Bc = sm + 12288 + p * 8192;

    // B fragments for this wave's 32 cols
    bf16x8 bf0, bf1;
    {
      int row = wav * 32 + lrow;
      int cs = lgrp ^ (row & 3) ^ ((row >> 2) & 3);
      bf0 = *(const bf16x8*)&Bc[(row * 4 + cs) * 8];
      row += 16;
      cs = lgrp ^ (row & 3) ^ ((row >> 2) & 3);
      bf1 = *(const bf16x8*)&Bc[(row * 4 + cs) * 8];
    }
    __builtin_amdgcn_s_setprio(1);
#pragma unroll
    for (int i = 0; i < 8; ++i) {
      int row = i * 16 + lrow;
      int cs = lgrp ^ (row & 3) ^ ((row >> 2) & 3);
      bf16x8 af = *(const bf16x8*)&Ac[(row * 4 + cs) * 8];
      acc[i][0] = __builtin_amdgcn_mfma_f32_16x16x32_bf16(af, bf0, acc[i][0], 0, 0, 0);
      acc[i][1] = __builtin_amdgcn_mfma_f32_16x16x32_bf16(af, bf1, acc[i][1], 0, 0, 0);
    }
    __builtin_amdgcn_s_setprio(0);

    if (t + 1 < NT) {
      if (t + 2 < NT) { asm volatile("s_waitcnt vmcnt(3)" ::: "memory"); }
      else            { asm volatile("s_waitcnt vmcnt(0)" ::: "memory"); }
      __builtin_amdgcn_s_barrier();
      asm volatile("" ::: "memory");
    }
  }

  // ---- routed scatter epilogue (routing hoisted per j) ----
#pragma unroll
  for (int j = 0; j < 2; ++j) {
    int f = n0 + wav * 32 + j * 16 + lrow;
    unsigned short* dstj; float sc;
    {
      unsigned short* dst; int h, d;
      if (f < 1920)      { h = f / 120; d = f - h * 120; dst = Qb; sc = lws[h] * QSC; }
      else if (f < 3840) { int g = f - 1920; h = g / 120; d = g - h * 120; dst = Kb; sc = lws[h]; }
      else if (f < 5888) { int g = f - 3840; h = g >> 7; d = g & 127; dst = Vb; sc = 1.f; }
      else if (f < 6016) { int g = f - 5888; h = g >> 3; d = 120 + (g & 7);
                           if (lra[h]) { dst = Kb; sc = lwr[h]; }
                           else        { dst = Qb; sc = lws[h] * QSC; } }
      else               { int g = f - 6016; h = g >> 3; d = 120 + (g & 7);
                           if (lra[h]) { dst = Qb; sc = lwr[h] * QSC; }
                           else        { dst = Kb; sc = lws[h]; } }
      dstj = dst + h * 262144 + d;
    }
#pragma unroll
    for (int i = 0; i < 8; ++i)
#pragma unroll
      for (int r = 0; r < 4; ++r) {
        int m = m0 + i * 16 + lgrp * 4 + r;
        int b = m >> 11, tq = m & 2047;
        dstj[(size_t)b * 4194304 + tq * 128] = f2bf(acc[i][j][r] * sc);
      }
  }
}

// ---------------------------------------------------------------------------
// Round-4 proven 128x128 / 256-thread GEMM (static 33KB LDS) — used for proj.
// ---------------------------------------------------------------------------
template <int MODE>
__global__ __launch_bounds__(256)
void gemm_bf16_sm(const unsigned short* __restrict__ A, const unsigned short* __restrict__ Bw,
                  float* __restrict__ out, int N, int K)
{
  __shared__ unsigned short As[128 * 64];
  __shared__ unsigned short Bs[128 * 64];

  const int tid  = threadIdx.x;
  const int lane = tid & 63;
  const int w    = tid >> 6;
  const int wr   = w >> 1, wc = w & 1;
  const int lrow = lane & 15, lgrp = lane >> 4;
  const int m0 = blockIdx.y * 128;
  const int n0 = blockIdx.x * 128;

  f32x4 acc[4][4] = {};

  for (int kt = 0; kt < K; kt += 64) {
#pragma unroll
    for (int c = 0; c < 4; ++c) {
      int base16 = (c * 4 + w) * 64;
      int o16 = base16 + lane;
      int rr = o16 >> 3, cc = o16 & 7;
      int csw = (cc ^ (rr & 7)) << 3;
      gload16(A  + (size_t)(m0 + rr) * K + kt + csw, As + base16 * 8);
      gload16(Bw + (size_t)(n0 + rr) * K + kt + csw, Bs + base16 * 8);
    }
    __syncthreads();

#pragma unroll
    for (int s = 0; s < 2; ++s) {
      bf16x8 af[4], bfr[4];
#pragma unroll
      for (int i = 0; i < 4; ++i) {
        int row = wr * 64 + i * 16 + lrow;
        int ch  = s * 4 + lgrp;
        af[i]  = *(const bf16x8*)&As[row * 64 + ((ch ^ (row & 7)) << 3)];
        int col = wc * 64 + i * 16 + lrow;
        bfr[i] = *(const bf16x8*)&Bs[col * 64 + ((ch ^ (col & 7)) << 3)];
      }
#pragma unroll
      for (int i = 0; i < 4; ++i)
#pragma unroll
        for (int j = 0; j < 4; ++j)
          acc[i][j] = __builtin_amdgcn_mfma_f32_16x16x32_bf16(af[i], bfr[j], acc[i][j], 0, 0, 0);
    }
    __syncthreads();
  }

#pragma unroll
  for (int i = 0; i < 4; ++i)
#pragma unroll
    for (int r = 0; r < 4; ++r) {
      int m = m0 + wr * 64 + i * 16 + lgrp * 4 + r;
#pragma unroll
      for (int j = 0; j < 4; ++j) {
        int n = n0 + wc * 64 + j * 16 + lrow;
        out[(size_t)m * N + n] = acc[i][j][r];
      }
    }
}

// ---------------------------------------------------------------------------
// V[bh][t][d] -> Vt[bh][d][t] (bf16)
// ---------------------------------------------------------------------------
__global__ __launch_bounds__(256)
void vtrans(const unsigned short* __restrict__ Vb, unsigned short* __restrict__ Vtb)
{
  __shared__ unsigned short Vs[64 * 128];
  const int tid = threadIdx.x;
  const int bh = blockIdx.y, t0 = blockIdx.x * 64;
  const unsigned short* src = Vb + ((size_t)bh * Tt + t0) * DH;
#pragma unroll
  for (int c = 0; c < 4; ++c) {
    int u = c * 256 + tid;
    int row = u >> 4, ch = u & 15;
    *(uint4*)&Vs[row * 128 + ch * 8] = *(const uint4*)&src[(size_t)row * DH + ch * 8];
  }
  __syncthreads();
  unsigned short* dstb = Vtb + (size_t)bh * DH * Tt + t0;
#pragma unroll
  for (int c = 0; c < 4; ++c) {
    int u = c * 256 + tid;
    int d = u & 127, tc = u >> 7;
    unsigned short tmp[8];
#pragma unroll
    for (int j = 0; j < 8; ++j) tmp[j] = Vs[(tc * 8 + j) * 128 + d];
    *(uint4*)&dstb[(size_t)d * Tt + tc * 8] = *(uint4*)tmp;
  }
}

// ---------------------------------------------------------------------------
// MFMA flash attention, pair-balanced (unchanged from round 4/5).
// ---------------------------------------------------------------------------
__global__ __launch_bounds__(512)
void attn_mfma(const unsigned short* __restrict__ Qb, const unsigned short* __restrict__ Kb,
               const unsigned short* __restrict__ Vtb, unsigned short* __restrict__ attb)
{
  extern __shared__ unsigned short smem[];
  unsigned short* KT = smem;               // 2 x [64][128]
  unsigned short* VT = smem + 2 * 8192;    // 2 x [128][64]
  unsigned short* PB = smem + 4 * 8192;    // 8 waves x [16][64]

  const int tid = threadIdx.x, lane = tid & 63, wav = tid >> 6;
  const int lrow = lane & 15, lgrp = lane >> 4;
  const int bid = blockIdx.x;
  const int xs  = bid & 7;
  const int rem = bid >> 3;
  const int bh  = xs + ((rem & 3) << 3);
  const int pr  = rem >> 2;

  const unsigned short* Qh = Qb  + (size_t)bh * Tt * DH;
  const unsigned short* Kh = Kb  + (size_t)bh * Tt * DH;
  const unsigned short* Vh = Vtb + (size_t)bh * DH * Tt;
  const int b = bh >> 4, h = bh & 15;

  unsigned short* Pw = PB + wav * 1024;

  auto stage = [&](int buf, int kv0) {
    unsigned short* Kd = KT + buf * 8192;
    unsigned short* Vd = VT + buf * 8192;
#pragma unroll
    for (int s = 0; s < 2; ++s) {
      int base16 = s * 512 + wav * 64;
      int o16 = base16 + lane;
      { int rr = o16 >> 4, cc = o16 & 15;
        gload16(Kh + (size_t)(kv0 + rr) * DH + ((cc ^ (rr & 7)) << 3), Kd + base16 * 8); }
      { int rr = o16 >> 3, cc = o16 & 7;
        gload16(Vh + (size_t)rr * Tt + kv0 + ((cc ^ (rr & 7)) << 3), Vd + base16 * 8); }
    }
  };

  int cur = 0;
  stage(0, 0);

  for (int ph = 0; ph < 2; ++ph) {
    const int qt = ph ? (15 - pr) : pr;
    const int q0 = qt * 128;
    const int nt = 2 * (qt + 1);

    bf16x8 qf[4];
#pragma unroll
    for (int ks = 0; ks < 4; ++ks)
      qf[ks] = *(const bf16x8*)(Qh + (size_t)(q0 + wav * 16 + lrow) * DH + ks * 32 + lgrp * 8);

    f32x4 o[8] = {};
    float mrun[4], lrun[4];
#pragma unroll
    for (int r = 0; r < 4; ++r) { mrun[r] = -INFINITY; lrun[r] = 0.f; }

    for (int t = 0; t < nt; ++t) {
      const int kv0 = t * 64;
      __syncthreads();
      bool more = (t + 1 < nt);
      if (more)            stage(cur ^ 1, kv0 + 64);
      else if (ph == 0)    stage(cur ^ 1, 0);

      const unsigned short* Kc = KT + cur * 8192;
      const unsigned short* Vc = VT + cur * 8192;

      f32x4 sv[4] = {};
#pragma unroll
      for (int ks = 0; ks < 4; ++ks)
#pragma unroll
        for (int j = 0; j < 4; ++j) {
          int krow = j * 16 + lrow;
          int ch   = ks * 4 + lgrp;
          bf16x8 kf = *(const bf16x8*)&Kc[krow * 128 + ((ch ^ (krow & 7)) << 3)];
          sv[j] = __builtin_amdgcn_mfma_f32_16x16x32_bf16(qf[ks], kf, sv[j], 0, 0, 0);
        }

      const bool domask = (kv0 >= q0);
      float sc[4];
#pragma unroll
      for (int r = 0; r < 4; ++r) {
        if (domask) {
          int qrow = q0 + wav * 16 + lgrp * 4 + r;
#pragma unroll
          for (int j = 0; j < 4; ++j) {
            int kv = kv0 + j * 16 + lrow;
            if (kv > qrow) sv[j][r] = -INFINITY;
          }
        }
        float m_ = fmaxf(fmaxf(sv[0][r], sv[1][r]), fmaxf(sv[2][r], sv[3][r]));
        m_ = fmaxf(m_, __shfl_xor(m_, 1));
        m_ = fmaxf(m_, __shfl_xor(m_, 2));
        m_ = fmaxf(m_, __shfl_xor(m_, 4));
        m_ = fmaxf(m_, __shfl_xor(m_, 8));
        float mn = fmaxf(mrun[r], m_);
        sc[r] = __expf(mrun[r] - mn);
        mrun[r] = mn;
        float rs = 0.f;
#pragma unroll
        for (int j = 0; j < 4; ++j) {
          float p = __expf(sv[j][r] - mn);
          sv[j][r] = p;
          rs += p;
        }
        rs += __shfl_xor(rs, 1);
        rs += __shfl_xor(rs, 2);
        rs += __shfl_xor(rs, 4);
        rs += __shfl_xor(rs, 8);
        lrun[r] = lrun[r] * sc[r] + rs;
      }

#pragma unroll
      for (int n = 0; n < 8; ++n)
#pragma unroll
        for (int r = 0; r < 4; ++r) o[n][r] *= sc[r];

#pragma unroll
      for (int j = 0; j < 4; ++j)
#pragma unroll
        for (int r = 0; r < 4; ++r) {
          int row = lgrp * 4 + r;
          int col = j * 16 + lrow;
          int ch  = col >> 3;
          Pw[row * 64 + ((ch ^ (row & 7)) << 3) + (col & 7)] = f2bf(sv[j][r]);
        }

#pragma unroll
      for (int ks = 0; ks < 2; ++ks) {
        int ch = ks * 4 + lgrp;
        bf16x8 pa = *(const bf16x8*)&Pw[lrow * 64 + ((ch ^ (lrow & 7)) << 3)];
#pragma unroll
        for (int n = 0; n < 8; ++n) {
          int d = n * 16 + lrow;
          bf16x8 vf = *(const bf16x8*)&Vc[d * 64 + ((ch ^ (d & 7)) << 3)];
          o[n] = __builtin_amdgcn_mfma_f32_16x16x32_bf16(pa, vf, o[n], 0, 0, 0);
        }
      }
      cur ^= 1;
    }

#pragma unroll
    for (int r = 0; r < 4; ++r) {
      float inv = 1.f / lrun[r];
      int tg = q0 + wav * 16 + lgrp * 4 + r;
      unsigned short* dst = attb + ((size_t)(b * Tt + tg) * Cc) + h * DH;
#pragma unroll
      for (int n = 0; n < 8; ++n)
        dst[n * 16 + lrow] = f2bf(o[n][r] * inv);
    }
  }
}

// ---------------------------------------------------------------------------
extern "C" void kernel_launch(void* const* d_in, const int* in_sizes, int n_in,
                              void* d_out, int out_size, void* d_ws, size_t ws_size,
                              hipStream_t stream) {
  const float* x      = (const float*)d_in[0];
  const float* W_attn = (const float*)d_in[1];
  const float* W_proj = (const float*)d_in[2];
  const float* w_std  = (const float*)d_in[3];
  const float* w_rec  = (const float*)d_in[4];
  float* outp = (float*)d_out;

  unsigned short* wsb = (unsigned short*)d_ws;   // 67,108,864 bf16 elems = 128 MiB
  unsigned short* xb   = wsb;                 // 8,388,608
  unsigned short* Wab  = wsb + 8388608;       // 12,582,912
  unsigned short* Wpb  = wsb + 20971520;      // 4,194,304
  unsigned short* Qb   = wsb + 25165824;      // 8,388,608
  unsigned short* Kb   = wsb + 33554432;
  unsigned short* Vb   = wsb + 41943040;
  unsigned short* Vtb  = wsb + 50331648;
  unsigned short* attb = wsb + 58720256;

  f2bf_all<<<2048, 256, 0, stream>>>(x, W_attn, W_proj, wsb);

  // fused QKV GEMM: counted-vmcnt pipeline, 72KB dynamic LDS
  gemm1_pipe<<<dim3(FUSED / 256, Mm / 128), dim3(512), 73728, stream>>>(
      xb, Wab, Qb, Kb, Vb, w_std, w_rec, FUSED, Cc);

  vtrans<<<dim3(Tt / 64, Bb * Hh), dim3(256), 0, stream>>>(Vb, Vtb);

  attn_mfma<<<dim3(256), dim3(512), 81920, stream>>>(Qb, Kb, Vtb, attb);

  // proj GEMM: round-4 proven 128x128 kernel
  gemm_bf16_sm<0><<<dim3(Cc / 128, Mm / 128), dim3(256), 0, stream>>>(
      attb, Wpb, outp, Cc, Cc);
}